// Round 1
// baseline (1036.703 us; speedup 1.0000x reference)
//
#include <hip/hip_runtime.h>

#define L 2048
#define RNK 8
#define DV 128
#define NBH 32          // B*H = 4*8

typedef float  f32x4 __attribute__((ext_vector_type(4)));
typedef int    i32x4 __attribute__((ext_vector_type(4)));
typedef short  s16x8 __attribute__((ext_vector_type(8)));
typedef short  s16x4 __attribute__((ext_vector_type(4)));

// f32 -> bf16 bits, round-to-nearest-even (no NaN inputs here)
__device__ __forceinline__ short f2bf(float f) {
    union { float f; unsigned u; } x; x.f = f;
    unsigned r = x.u + 0x7fffu + ((x.u >> 16) & 1u);
    return (short)(r >> 16);
}

// ---------------------------------------------------------------------------
// Kernel A: scores (rank-8 dot, on the fly) + mask + softmax -> attn (f32)
// One wave per row; lane owns 32 cols as 8 x float4 chunks (c = j*256 + lane*4).
// Block = 256 threads = 4 waves; each wave does 8 rows -> 32 rows/block.
// ---------------------------------------------------------------------------
__global__ __launch_bounds__(256) void softmax_kernel(
    const float* __restrict__ a1,   // [BH, L, R]
    const float* __restrict__ a2,   // [BH, R, L]
    const int*   __restrict__ mask, // [B, 1, L, L]
    float*       __restrict__ attn) // [BH, L, L]
{
    const int lane = threadIdx.x & 63;
    const int wv   = threadIdx.x >> 6;
    const long row0 = (long)blockIdx.x * 32 + (long)wv * 8;

    for (int it = 0; it < 8; ++it) {
        const long row = row0 + it;           // [0, 65536)
        const int bh = (int)(row >> 11);
        const int l  = (int)(row & (L - 1));
        const int b  = bh >> 3;

        const float* a1p = a1 + ((long)bh * L + l) * RNK;
        float a1v[RNK];
#pragma unroll
        for (int r = 0; r < RNK; ++r) a1v[r] = a1p[r];

        const float* a2p = a2 + (long)bh * RNK * L;
        const int*   mp  = mask + ((long)b * L + l) * L;

        float s[8][4];
#pragma unroll
        for (int j = 0; j < 8; ++j) {
            const int c = j * 256 + lane * 4;
            f32x4 sc;
            sc[0] = 0.f; sc[1] = 0.f; sc[2] = 0.f; sc[3] = 0.f;
#pragma unroll
            for (int r = 0; r < RNK; ++r) {
                const f32x4 av = *(const f32x4*)(a2p + (long)r * L + c);
#pragma unroll
                for (int q = 0; q < 4; ++q) sc[q] += a1v[r] * av[q];
            }
            const i32x4 mm = *(const i32x4*)(mp + c);
#pragma unroll
            for (int q = 0; q < 4; ++q)
                s[j][q] = (mm[q] == 0) ? -1e9f : sc[q];
        }

        // row max (wave-wide)
        float mx = s[0][0];
#pragma unroll
        for (int j = 0; j < 8; ++j)
#pragma unroll
            for (int q = 0; q < 4; ++q) mx = fmaxf(mx, s[j][q]);
#pragma unroll
        for (int d = 1; d < 64; d <<= 1) mx = fmaxf(mx, __shfl_xor(mx, d, 64));

        // exp + row sum
        float sum = 0.f;
#pragma unroll
        for (int j = 0; j < 8; ++j)
#pragma unroll
            for (int q = 0; q < 4; ++q) {
                const float e = __expf(s[j][q] - mx);
                s[j][q] = e;
                sum += e;
            }
#pragma unroll
        for (int d = 1; d < 64; d <<= 1) sum += __shfl_xor(sum, d, 64);

        const float inv = 1.f / sum;
        float* op = attn + (long)row * L;
#pragma unroll
        for (int j = 0; j < 8; ++j) {
            f32x4 o;
#pragma unroll
            for (int q = 0; q < 4; ++q) o[q] = s[j][q] * inv;
            *(f32x4*)(op + j * 256 + lane * 4) = o;
        }
    }
}

// ---------------------------------------------------------------------------
// Kernel B: out = attn @ v per (b,h). Batched GEMM M=2048, N=128, K=2048.
// Block: 128(M) x 128(N=full DV) tile, 256 threads = 4 waves (2x2 of 64x64).
// Reg-stage f32 -> bf16 into LDS (stride 72 bf16 = balanced banks),
// V stored transposed [d][k] so B-fragments are contiguous 16B reads.
// mfma_f32_16x16x32_bf16; C/D layout: col=lane&15, row=(lane>>4)*4+reg.
// ---------------------------------------------------------------------------
#define BK 64
#define SA 72   // LDS leading stride in bf16 elements (64 + 8 pad)

__global__ __launch_bounds__(256) void pv_kernel(
    const float* __restrict__ attn, // [BH, L, L]
    const float* __restrict__ v,    // [BH, L, DV]
    float*       __restrict__ out)  // [BH, L, DV]
{
    __shared__ short As[128 * SA];  // [row][k]
    __shared__ short Vs[DV * SA];   // [d][k]  (transposed)

    const int t    = threadIdx.x;
    const int lane = t & 63;
    const int wv   = t >> 6;
    const int wr   = wv >> 1;       // wave row (0..1)
    const int wc   = wv & 1;        // wave col (0..1)
    const int bh   = blockIdx.y;
    const int mt   = blockIdx.x;

    const float* Ag = attn + (size_t)bh * L * L + (size_t)mt * 128 * L;
    const float* Vg = v    + (size_t)bh * L * DV;

    f32x4 acc[4][4];
#pragma unroll
    for (int m = 0; m < 4; ++m)
#pragma unroll
        for (int n = 0; n < 4; ++n)
#pragma unroll
            for (int i = 0; i < 4; ++i) acc[m][n][i] = 0.f;

    const int ar = t >> 4;          // A stage: row offset 0..15
    const int ak = (t & 15) * 4;    // A stage: k offset
    const int vd = (t & 31) * 4;    // V stage: d base
    const int vk = (t >> 5) * 8;    // V stage: k base

    for (int k0 = 0; k0 < L; k0 += BK) {
        // ---- stage A tile: 128 x 64 f32 -> bf16 LDS
#pragma unroll
        for (int p = 0; p < 8; ++p) {
            const int rrow = p * 16 + ar;
            const f32x4 f = *(const f32x4*)(Ag + (size_t)rrow * L + k0 + ak);
            s16x4 pk;
#pragma unroll
            for (int q = 0; q < 4; ++q) pk[q] = f2bf(f[q]);
            *(s16x4*)(As + rrow * SA + ak) = pk;   // ds_write_b64, 8B aligned
        }
        // ---- stage V tile: 64 x 128 f32 -> transposed bf16 LDS
        f32x4 vv[8];
#pragma unroll
        for (int j = 0; j < 8; ++j)
            vv[j] = *(const f32x4*)(Vg + (size_t)(k0 + vk + j) * DV + vd);
#pragma unroll
        for (int c = 0; c < 4; ++c) {
            s16x8 pk;
#pragma unroll
            for (int j = 0; j < 8; ++j) pk[j] = f2bf(vv[j][c]);
            *(s16x8*)(Vs + (vd + c) * SA + vk) = pk; // ds_write_b128, 16B aligned
        }
        __syncthreads();

        // ---- compute: 2 k-subtiles of 32, 16 MFMAs each
#pragma unroll
        for (int kk = 0; kk < 2; ++kk) {
            const int kb = kk * 32 + (lane >> 4) * 8;
            s16x8 af[4], bf[4];
#pragma unroll
            for (int m = 0; m < 4; ++m)
                af[m] = *(const s16x8*)(As + (wr * 64 + m * 16 + (lane & 15)) * SA + kb);
#pragma unroll
            for (int n = 0; n < 4; ++n)
                bf[n] = *(const s16x8*)(Vs + (wc * 64 + n * 16 + (lane & 15)) * SA + kb);
#pragma unroll
            for (int m = 0; m < 4; ++m)
#pragma unroll
                for (int n = 0; n < 4; ++n)
                    acc[m][n] = __builtin_amdgcn_mfma_f32_16x16x32_bf16(
                        af[m], bf[n], acc[m][n], 0, 0, 0);
        }
        __syncthreads();
    }

    // ---- epilogue: C/D layout col=lane&15, row=(lane>>4)*4+i
    float* Og = out + (size_t)bh * L * DV + (size_t)mt * 128 * DV;
#pragma unroll
    for (int m = 0; m < 4; ++m)
#pragma unroll
        for (int n = 0; n < 4; ++n)
#pragma unroll
            for (int i = 0; i < 4; ++i) {
                const int rrow = wr * 64 + m * 16 + (lane >> 4) * 4 + i;
                const int col  = wc * 64 + n * 16 + (lane & 15);
                Og[(size_t)rrow * DV + col] = acc[m][n][i];
            }
}

extern "C" void kernel_launch(void* const* d_in, const int* in_sizes, int n_in,
                              void* d_out, int out_size, void* d_ws, size_t ws_size,
                              hipStream_t stream) {
    const float* v    = (const float*)d_in[0];
    const float* a1   = (const float*)d_in[1];
    const float* a2   = (const float*)d_in[2];
    const int*   mask = (const int*)d_in[3];
    // d_in[4] = len_q (always 2048 for this benchmark config)

    float* out  = (float*)d_out;
    float* attn = out + (size_t)NBH * L * DV;   // out is [32,2048,128]; attn follows

    // Kernel A: 65536 rows total, 32 rows/block
    softmax_kernel<<<2048, 256, 0, stream>>>(a1, a2, mask, attn);
    // Kernel B: 16 M-tiles x 32 batches
    pv_kernel<<<dim3(16, NBH), 256, 0, stream>>>(attn, v, out);
}

// Round 3
// 885.049 us; speedup vs baseline: 1.1714x; 1.1714x over previous
//
#include <hip/hip_runtime.h>

#define L 2048
#define RNK 8
#define DV 128
#define NBH 32          // B*H = 4*8

typedef float         f32x4 __attribute__((ext_vector_type(4)));
typedef int           i32x4 __attribute__((ext_vector_type(4)));
typedef short         s16x8 __attribute__((ext_vector_type(8)));
typedef short         s16x4 __attribute__((ext_vector_type(4)));
typedef unsigned int  u32;

// f32 -> bf16 bits, round-to-nearest-even
__device__ __forceinline__ short f2bf(float f) {
    union { float f; unsigned u; } x; x.f = f;
    unsigned r = x.u + 0x7fffu + ((x.u >> 16) & 1u);
    return (short)(r >> 16);
}

// ---------------------------------------------------------------------------
// Kernel A: one block (256 threads) per row. Thread owns 8 cols as 2 f32x4
// chunks (c = h*1024 + t*4). Wave shfl reduce + 8-float LDS for block reduce.
// Writes f32 attn (output) and optionally bf16 attn copy (for pv_bf16).
// ---------------------------------------------------------------------------
__global__ __launch_bounds__(256, 4) void softmax_kernel2(
    const float* __restrict__ a1,   // [BH, L, R]
    const float* __restrict__ a2,   // [BH, R, L]
    const int*   __restrict__ mask, // [B, 1, L, L]
    float*       __restrict__ attn, // [BH, L, L]
    short*       __restrict__ attn_bf) // [BH, L, L] bf16, may be null
{
    __shared__ float red[8];
    const int t   = threadIdx.x;
    const long row = blockIdx.x;            // 0..65535
    const int bh = (int)(row >> 11);
    const int l  = (int)(row & (L - 1));
    const int b  = bh >> 3;

    const float* a1p = a1 + ((long)bh * L + l) * RNK;
    float a1v[RNK];
    {
        const f32x4 u = *(const f32x4*)a1p;
        const f32x4 w = *(const f32x4*)(a1p + 4);
#pragma unroll
        for (int q = 0; q < 4; ++q) { a1v[q] = u[q]; a1v[4 + q] = w[q]; }
    }
    const float* a2p = a2 + (long)bh * RNK * L;
    const int*   mp  = mask + ((long)b * L + l) * L;

    float s[2][4];
#pragma unroll
    for (int h = 0; h < 2; ++h) {
        const int c = h * 1024 + t * 4;
        f32x4 sc;
        sc[0] = 0.f; sc[1] = 0.f; sc[2] = 0.f; sc[3] = 0.f;
#pragma unroll
        for (int r = 0; r < RNK; ++r) {
            const f32x4 av = *(const f32x4*)(a2p + (long)r * L + c);
#pragma unroll
            for (int q = 0; q < 4; ++q) sc[q] += a1v[r] * av[q];
        }
        const i32x4 mm = *(const i32x4*)(mp + c);
#pragma unroll
        for (int q = 0; q < 4; ++q)
            s[h][q] = (mm[q] == 0) ? -1e9f : sc[q];
    }

    // block max
    float mx = s[0][0];
#pragma unroll
    for (int h = 0; h < 2; ++h)
#pragma unroll
        for (int q = 0; q < 4; ++q) mx = fmaxf(mx, s[h][q]);
#pragma unroll
    for (int d = 1; d < 64; d <<= 1) mx = fmaxf(mx, __shfl_xor(mx, d, 64));
    if ((t & 63) == 0) red[t >> 6] = mx;
    __syncthreads();
    mx = fmaxf(fmaxf(red[0], red[1]), fmaxf(red[2], red[3]));

    // exp + block sum
    float sum = 0.f;
#pragma unroll
    for (int h = 0; h < 2; ++h)
#pragma unroll
        for (int q = 0; q < 4; ++q) {
            const float e = __expf(s[h][q] - mx);
            s[h][q] = e;
            sum += e;
        }
#pragma unroll
    for (int d = 1; d < 64; d <<= 1) sum += __shfl_xor(sum, d, 64);
    if ((t & 63) == 0) red[4 + (t >> 6)] = sum;
    __syncthreads();
    sum = (red[4] + red[5]) + (red[6] + red[7]);
    const float inv = 1.f / sum;

    float* op = attn + (long)row * L;
#pragma unroll
    for (int h = 0; h < 2; ++h) {
        const int c = h * 1024 + t * 4;
        f32x4 o;
#pragma unroll
        for (int q = 0; q < 4; ++q) o[q] = s[h][q] * inv;
        *(f32x4*)(op + c) = o;
        if (attn_bf) {
            s16x4 pk;
#pragma unroll
            for (int q = 0; q < 4; ++q) pk[q] = f2bf(o[q]);
            *(s16x4*)(attn_bf + (long)row * L + c) = pk;
        }
    }
}

// ---------------------------------------------------------------------------
// vt_convert: v [bh][k][d] f32 -> vt [bh][d][k] bf16 (transposed, for B-frags)
// grid (32 ktiles, 32 bh), block 256. Tile 64k x 128d via LDS.
// ---------------------------------------------------------------------------
__global__ __launch_bounds__(256, 4) void vt_convert(
    const float* __restrict__ v, short* __restrict__ vt)
{
    __shared__ short T[DV][72];     // [d][k], padded stride
    const int bh = blockIdx.y;
    const int k0 = blockIdx.x * 64;
    const int t  = threadIdx.x;

    const float* src = v + (size_t)bh * L * DV;
    const int kr = t >> 5;          // 0..7
    const int dc = (t & 31) * 4;    // 0..124
#pragma unroll
    for (int p = 0; p < 8; ++p) {
        const int k = p * 8 + kr;
        const f32x4 f = *(const f32x4*)(src + (size_t)(k0 + k) * DV + dc);
#pragma unroll
        for (int q = 0; q < 4; ++q) T[dc + q][k] = f2bf(f[q]);
    }
    __syncthreads();

    short* dst = vt + (size_t)bh * DV * L;
    const int dr = t >> 1;          // 0..127
    const int kc = (t & 1) * 32;    // 0 / 32
#pragma unroll
    for (int j = 0; j < 4; ++j)
        *(s16x8*)(dst + (size_t)dr * L + k0 + kc + j * 8) =
            *(const s16x8*)(&T[dr][kc + j * 8]);
}

// ---------------------------------------------------------------------------
// Kernel B (primary): out = attn_bf @ v. bf16 inputs, m97-style structure:
// global_load_lds width 16 into linear LDS, BK=64, 128x128 tile, 4 waves 2x2.
// LDS dest is base + 16*t bytes (wave-uniform + lane*size) as HW requires.
// ---------------------------------------------------------------------------
__global__ __launch_bounds__(256, 2) void pv_bf16(
    const short* __restrict__ attn_bf, // [BH, L, L] bf16
    const short* __restrict__ vt,      // [BH, DV, L] bf16 (transposed)
    float*       __restrict__ out)     // [BH, L, DV]
{
    __shared__ short As[128 * 64];  // [row m][k] linear
    __shared__ short Vs[128 * 64];  // [row d][k] linear

    const int t    = threadIdx.x;
    const int lane = t & 63;
    const int wv   = t >> 6;
    const int wr   = wv >> 1;
    const int wc   = wv & 1;
    const int bh   = blockIdx.y;
    const int mt   = blockIdx.x;

    const short* Ab = attn_bf + ((size_t)bh * L + (size_t)mt * 128) * L;
    const short* Vb = vt + (size_t)bh * DV * L;

    f32x4 acc[4][4];
#pragma unroll
    for (int m = 0; m < 4; ++m)
#pragma unroll
        for (int n = 0; n < 4; ++n)
#pragma unroll
            for (int i = 0; i < 4; ++i) acc[m][n][i] = 0.f;

    const int sr = t >> 3;          // 0..31
    const int sc = (t & 7) * 8;     // element offset (x2B = 16B steps)

    for (int k0 = 0; k0 < L; k0 += 64) {
#pragma unroll
        for (int p = 0; p < 4; ++p) {
            const int row = p * 32 + sr;
            __builtin_amdgcn_global_load_lds(
                (const u32*)(Ab + (size_t)row * L + k0 + sc),
                (u32*)(As + row * 64 + sc), 16, 0, 0);
            __builtin_amdgcn_global_load_lds(
                (const u32*)(Vb + (size_t)row * L + k0 + sc),
                (u32*)(Vs + row * 64 + sc), 16, 0, 0);
        }
        __syncthreads();

#pragma unroll
        for (int kk = 0; kk < 2; ++kk) {
            const int kb = kk * 32 + (lane >> 4) * 8;
            s16x8 af[4], bf[4];
#pragma unroll
            for (int m = 0; m < 4; ++m)
                af[m] = *(const s16x8*)(As + (wr * 64 + m * 16 + (lane & 15)) * 64 + kb);
#pragma unroll
            for (int n = 0; n < 4; ++n)
                bf[n] = *(const s16x8*)(Vs + (wc * 64 + n * 16 + (lane & 15)) * 64 + kb);
#pragma unroll
            for (int m = 0; m < 4; ++m)
#pragma unroll
                for (int n = 0; n < 4; ++n)
                    acc[m][n] = __builtin_amdgcn_mfma_f32_16x16x32_bf16(
                        af[m], bf[n], acc[m][n], 0, 0, 0);
        }
        __syncthreads();
    }

    float* Og = out + (size_t)bh * L * DV + (size_t)mt * 128 * DV;
#pragma unroll
    for (int m = 0; m < 4; ++m)
#pragma unroll
        for (int n = 0; n < 4; ++n)
#pragma unroll
            for (int i = 0; i < 4; ++i) {
                const int rrow = wr * 64 + m * 16 + (lane >> 4) * 4 + i;
                const int col  = wc * 64 + n * 16 + (lane & 15);
                Og[(size_t)rrow * DV + col] = acc[m][n][i];
            }
}

// ---------------------------------------------------------------------------
// Kernel B (fallback, ws too small): f32 attn input, reg-staged cvt
// ---------------------------------------------------------------------------
#define SA 72
__global__ __launch_bounds__(256) void pv_kernel(
    const float* __restrict__ attn,
    const float* __restrict__ v,
    float*       __restrict__ out)
{
    __shared__ short As[128 * SA];
    __shared__ short Vs[DV * SA];

    const int t    = threadIdx.x;
    const int lane = t & 63;
    const int wv   = t >> 6;
    const int wr   = wv >> 1;
    const int wc   = wv & 1;
    const int bh   = blockIdx.y;
    const int mt   = blockIdx.x;

    const float* Ag = attn + (size_t)bh * L * L + (size_t)mt * 128 * L;
    const float* Vg = v    + (size_t)bh * L * DV;

    f32x4 acc[4][4];
#pragma unroll
    for (int m = 0; m < 4; ++m)
#pragma unroll
        for (int n = 0; n < 4; ++n)
#pragma unroll
            for (int i = 0; i < 4; ++i) acc[m][n][i] = 0.f;

    const int ar = t >> 4;
    const int ak = (t & 15) * 4;
    const int vd = (t & 31) * 4;
    const int vk = (t >> 5) * 8;

    for (int k0 = 0; k0 < L; k0 += 64) {
#pragma unroll
        for (int p = 0; p < 8; ++p) {
            const int rrow = p * 16 + ar;
            const f32x4 f = *(const f32x4*)(Ag + (size_t)rrow * L + k0 + ak);
            s16x4 pk;
#pragma unroll
            for (int q = 0; q < 4; ++q) pk[q] = f2bf(f[q]);
            *(s16x4*)(As + rrow * SA + ak) = pk;
        }
        f32x4 vv[8];
#pragma unroll
        for (int j = 0; j < 8; ++j)
            vv[j] = *(const f32x4*)(Vg + (size_t)(k0 + vk + j) * DV + vd);
#pragma unroll
        for (int c = 0; c < 4; ++c) {
            s16x8 pk;
#pragma unroll
            for (int j = 0; j < 8; ++j) pk[j] = f2bf(vv[j][c]);
            *(s16x8*)(Vs + (vd + c) * SA + vk) = pk;
        }
        __syncthreads();

#pragma unroll
        for (int kk = 0; kk < 2; ++kk) {
            const int kb = kk * 32 + (lane >> 4) * 8;
            s16x8 af[4], bf[4];
#pragma unroll
            for (int m = 0; m < 4; ++m)
                af[m] = *(const s16x8*)(As + (wr * 64 + m * 16 + (lane & 15)) * SA + kb);
#pragma unroll
            for (int n = 0; n < 4; ++n)
                bf[n] = *(const s16x8*)(Vs + (wc * 64 + n * 16 + (lane & 15)) * SA + kb);
#pragma unroll
            for (int m = 0; m < 4; ++m)
#pragma unroll
                for (int n = 0; n < 4; ++n)
                    acc[m][n] = __builtin_amdgcn_mfma_f32_16x16x32_bf16(
                        af[m], bf[n], acc[m][n], 0, 0, 0);
        }
        __syncthreads();
    }

    float* Og = out + (size_t)bh * L * DV + (size_t)mt * 128 * DV;
#pragma unroll
    for (int m = 0; m < 4; ++m)
#pragma unroll
        for (int n = 0; n < 4; ++n)
#pragma unroll
            for (int i = 0; i < 4; ++i) {
                const int rrow = wr * 64 + m * 16 + (lane >> 4) * 4 + i;
                const int col  = wc * 64 + n * 16 + (lane & 15);
                Og[(size_t)rrow * DV + col] = acc[m][n][i];
            }
}

extern "C" void kernel_launch(void* const* d_in, const int* in_sizes, int n_in,
                              void* d_out, int out_size, void* d_ws, size_t ws_size,
                              hipStream_t stream) {
    const float* v    = (const float*)d_in[0];
    const float* a1   = (const float*)d_in[1];
    const float* a2   = (const float*)d_in[2];
    const int*   mask = (const int*)d_in[3];

    float* out  = (float*)d_out;
    float* attn = out + (size_t)NBH * L * DV;

    const size_t ATTN_BF_BYTES = (size_t)NBH * L * L * 2;   // 268,435,456
    const size_t VT_BYTES      = (size_t)NBH * DV * L * 2;  //  16,777,216
    const bool use_ws = (ws_size >= ATTN_BF_BYTES + VT_BYTES);

    short* attn_bf = use_ws ? (short*)d_ws : nullptr;
    short* vt      = use_ws ? (short*)((char*)d_ws + ATTN_BF_BYTES) : nullptr;

    softmax_kernel2<<<65536, 256, 0, stream>>>(a1, a2, mask, attn, attn_bf);
    if (use_ws) {
        vt_convert<<<dim3(32, NBH), 256, 0, stream>>>(v, vt);
        pv_bf16<<<dim3(16, NBH), 256, 0, stream>>>(attn_bf, vt, out);
    } else {
        pv_kernel<<<dim3(16, NBH), 256, 0, stream>>>(attn, v, out);
    }
}